// Round 4
// baseline (1285.939 us; speedup 1.0000x reference)
//
#include <hip/hip_runtime.h>
#include <hip/hip_bf16.h>

#define N_NODES 100000
#define NB 784   // buckets of 128 nodes: 784*128 = 100352 >= N_NODES
#define BSH 7
#define BMASK 127

// ---------------------------------------------------------------------------
// Fused dual-GEMM, layer 1:
//   h[r][c] = relu( mean1[r]@W1n[:,c] + x[r]@W1s[:,c] + b1[c] )
// ---------------------------------------------------------------------------
__global__ __launch_bounds__(256) void gemm1_k(
    const float* __restrict__ mean1, const float* __restrict__ x,
    const float* __restrict__ W1n, const float* __restrict__ W1s,
    const float* __restrict__ b1, float* __restrict__ h, int M) {
  __shared__ float Wn[64 * 64];
  __shared__ float Ws[64 * 64];
  const int tid = threadIdx.x;
  for (int i = tid; i < 64 * 64; i += 256) {
    Wn[i] = W1n[i];
    Ws[i] = W1s[i];
  }
  __syncthreads();

  const int col = tid & 63;
  const int g = tid >> 6;
  const long long row0 = (long long)blockIdx.x * 16 + g * 4;
  if (row0 >= M) return;

  float acc[4] = {0.f, 0.f, 0.f, 0.f};
#pragma unroll
  for (int k4 = 0; k4 < 16; ++k4) {
#pragma unroll
    for (int r = 0; r < 4; ++r) {
      float4 mv = ((const float4*)(mean1 + (row0 + r) * 64))[k4];
      float4 xv = ((const float4*)(x + (row0 + r) * 64))[k4];
      acc[r] = fmaf(mv.x, Wn[(4 * k4 + 0) * 64 + col], acc[r]);
      acc[r] = fmaf(mv.y, Wn[(4 * k4 + 1) * 64 + col], acc[r]);
      acc[r] = fmaf(mv.z, Wn[(4 * k4 + 2) * 64 + col], acc[r]);
      acc[r] = fmaf(mv.w, Wn[(4 * k4 + 3) * 64 + col], acc[r]);
      acc[r] = fmaf(xv.x, Ws[(4 * k4 + 0) * 64 + col], acc[r]);
      acc[r] = fmaf(xv.y, Ws[(4 * k4 + 1) * 64 + col], acc[r]);
      acc[r] = fmaf(xv.z, Ws[(4 * k4 + 2) * 64 + col], acc[r]);
      acc[r] = fmaf(xv.w, Ws[(4 * k4 + 3) * 64 + col], acc[r]);
    }
  }
  const float b = b1[col];
#pragma unroll
  for (int r = 0; r < 4; ++r)
    h[(row0 + r) * 64 + col] = fmaxf(acc[r] + b, 0.f);
}

// ---------------------------------------------------------------------------
// Fused dual-GEMM, layer 2: hn = h@W2n ; hs = h@W2s + b2
// ---------------------------------------------------------------------------
__global__ __launch_bounds__(256) void gemm2_k(
    const float* __restrict__ h, const float* __restrict__ W2n,
    const float* __restrict__ W2s, const float* __restrict__ b2,
    float* __restrict__ hn, float* __restrict__ hs, int M) {
  __shared__ float Wn[64 * 32];
  __shared__ float Ws[64 * 32];
  const int tid = threadIdx.x;
  for (int i = tid; i < 64 * 32; i += 256) {
    Wn[i] = W2n[i];
    Ws[i] = W2s[i];
  }
  __syncthreads();

  const int col = tid & 31;
  const int g = tid >> 5;
  const long long row0 = (long long)blockIdx.x * 32 + g * 4;
  if (row0 >= M) return;

  float an[4] = {0.f, 0.f, 0.f, 0.f};
  float as[4] = {0.f, 0.f, 0.f, 0.f};
#pragma unroll
  for (int k4 = 0; k4 < 16; ++k4) {
#pragma unroll
    for (int r = 0; r < 4; ++r) {
      float4 v = ((const float4*)(h + (row0 + r) * 64))[k4];
      an[r] = fmaf(v.x, Wn[(4 * k4 + 0) * 32 + col], an[r]);
      an[r] = fmaf(v.y, Wn[(4 * k4 + 1) * 32 + col], an[r]);
      an[r] = fmaf(v.z, Wn[(4 * k4 + 2) * 32 + col], an[r]);
      an[r] = fmaf(v.w, Wn[(4 * k4 + 3) * 32 + col], an[r]);
      as[r] = fmaf(v.x, Ws[(4 * k4 + 0) * 32 + col], as[r]);
      as[r] = fmaf(v.y, Ws[(4 * k4 + 1) * 32 + col], as[r]);
      as[r] = fmaf(v.z, Ws[(4 * k4 + 2) * 32 + col], as[r]);
      as[r] = fmaf(v.w, Ws[(4 * k4 + 3) * 32 + col], as[r]);
    }
  }
  const float b = b2[col];
#pragma unroll
  for (int r = 0; r < 4; ++r) {
    hn[(row0 + r) * 32 + col] = an[r];
    hs[(row0 + r) * 32 + col] = as[r] + b;
  }
}

// ------------------------- coarse bucket build -----------------------------
// 98 blocks x 1024 threads x 16 edges.
__global__ __launch_bounds__(1024) void bhist_k(const int* __restrict__ dst,
                                                unsigned* __restrict__ bcnt,
                                                int E) {
  __shared__ unsigned lh[NB];
  for (int i = threadIdx.x; i < NB; i += 1024) lh[i] = 0;
  __syncthreads();
  const int base = blockIdx.x * 16384;
#pragma unroll
  for (int it = 0; it < 16; ++it) {
    int e = base + it * 1024 + threadIdx.x;
    if (e < E) atomicAdd(&lh[((unsigned)dst[e]) >> BSH], 1u);
  }
  __syncthreads();
  for (int i = threadIdx.x; i < NB; i += 1024)
    if (lh[i]) atomicAdd(&bcnt[i], lh[i]);
}

__global__ __launch_bounds__(1024) void bscan_k(const unsigned* __restrict__ bcnt,
                                                unsigned* __restrict__ boff,
                                                unsigned* __restrict__ bcur) {
  __shared__ unsigned s[1024];
  const int tid = threadIdx.x;
  unsigned v = (tid < NB) ? bcnt[tid] : 0u;
  s[tid] = v;
  __syncthreads();
  for (int off = 1; off < 1024; off <<= 1) {
    unsigned t = (tid >= off) ? s[tid - off] : 0u;
    __syncthreads();
    s[tid] += t;
    __syncthreads();
  }
  unsigned ex = s[tid] - v;
  if (tid < NB) {
    boff[tid] = ex;
    bcur[tid] = ex;
  }
  if (tid == NB - 1) boff[NB] = ex + v;
}

// Scatter packed edges (src<<7 | dst&127) into bucket-ordered ep[].
// Each block reserves a contiguous run per bucket -> block-private write runs.
__global__ __launch_bounds__(1024) void bscatter_k(const int* __restrict__ src,
                                                   const int* __restrict__ dst,
                                                   unsigned* __restrict__ bcur,
                                                   unsigned* __restrict__ ep,
                                                   int E) {
  __shared__ unsigned lh[NB];
  __shared__ unsigned lbase[NB];
  for (int i = threadIdx.x; i < NB; i += 1024) lh[i] = 0;
  __syncthreads();
  const int base = blockIdx.x * 16384;
  unsigned short rank[16];
  unsigned short bb[16];
#pragma unroll
  for (int it = 0; it < 16; ++it) {
    int e = base + it * 1024 + threadIdx.x;
    if (e < E) {
      unsigned b = ((unsigned)dst[e]) >> BSH;
      bb[it] = (unsigned short)b;
      rank[it] = (unsigned short)atomicAdd(&lh[b], 1u);
    }
  }
  __syncthreads();
  for (int i = threadIdx.x; i < NB; i += 1024)
    lbase[i] = lh[i] ? atomicAdd(&bcur[i], lh[i]) : 0u;
  __syncthreads();
#pragma unroll
  for (int it = 0; it < 16; ++it) {
    int e = base + it * 1024 + threadIdx.x;
    if (e < E) {
      unsigned b = bb[it];
      ep[lbase[b] + rank[it]] =
          (((unsigned)src[e]) << BSH) | (((unsigned)dst[e]) & BMASK);
    }
  }
}

// ---------------------------------------------------------------------------
// Bucketed aggregate-mean: one block per bucket (128 nodes), LDS accumulator.
//   out[node][f] = (1/deg)*sum val[src][f]  (+ base[node][f] if ADD_BASE)
// Degree counted in the same pass. F=64: 1 edge/wave-step; F=32: 2.
// Unroll x4 -> 4 (8) row-loads in flight per wave.
// ---------------------------------------------------------------------------
template <int LOGF, bool ADD_BASE>
__global__ __launch_bounds__(256) void agg_k(
    const float* __restrict__ val, const unsigned* __restrict__ ep,
    const unsigned* __restrict__ boff, const float* __restrict__ basep,
    float* __restrict__ out, int N) {
  constexpr int F = 1 << LOGF;
  __shared__ float acc[128 * F];
  __shared__ unsigned ldeg[128];
  const int tid = threadIdx.x;
  for (int i = tid; i < 128 * F; i += 256) acc[i] = 0.f;
  if (tid < 128) ldeg[tid] = 0;
  __syncthreads();

  const unsigned beg = boff[blockIdx.x], end = boff[blockIdx.x + 1];
  const int w = tid >> 6;
  const int lane = tid & 63;

  if (LOGF == 6) {
    const int f = lane;
    unsigned j = beg + w * 4;
    for (; j + 4 <= end; j += 16) {
      unsigned p0 = ep[j], p1 = ep[j + 1], p2 = ep[j + 2], p3 = ep[j + 3];
      float v0 = val[(size_t)(p0 >> BSH) * 64 + f];
      float v1 = val[(size_t)(p1 >> BSH) * 64 + f];
      float v2 = val[(size_t)(p2 >> BSH) * 64 + f];
      float v3 = val[(size_t)(p3 >> BSH) * 64 + f];
      atomicAdd(&acc[(p0 & BMASK) * 64 + f], v0);
      atomicAdd(&acc[(p1 & BMASK) * 64 + f], v1);
      atomicAdd(&acc[(p2 & BMASK) * 64 + f], v2);
      atomicAdd(&acc[(p3 & BMASK) * 64 + f], v3);
      if (f == 0) {
        atomicAdd(&ldeg[p0 & BMASK], 1u);
        atomicAdd(&ldeg[p1 & BMASK], 1u);
        atomicAdd(&ldeg[p2 & BMASK], 1u);
        atomicAdd(&ldeg[p3 & BMASK], 1u);
      }
    }
    for (unsigned t = j; t < end && t < j + 4; ++t) {
      unsigned p = ep[t];
      float v = val[(size_t)(p >> BSH) * 64 + f];
      atomicAdd(&acc[(p & BMASK) * 64 + f], v);
      if (f == 0) atomicAdd(&ldeg[p & BMASK], 1u);
    }
  } else {
    const int half = lane >> 5;
    const int f = lane & 31;
    unsigned j = beg + w * 8;
    for (; j + 8 <= end; j += 32) {
      unsigned p0 = ep[j + 0 + half];
      unsigned p1 = ep[j + 2 + half];
      unsigned p2 = ep[j + 4 + half];
      unsigned p3 = ep[j + 6 + half];
      float v0 = val[(size_t)(p0 >> BSH) * 32 + f];
      float v1 = val[(size_t)(p1 >> BSH) * 32 + f];
      float v2 = val[(size_t)(p2 >> BSH) * 32 + f];
      float v3 = val[(size_t)(p3 >> BSH) * 32 + f];
      atomicAdd(&acc[(p0 & BMASK) * 32 + f], v0);
      atomicAdd(&acc[(p1 & BMASK) * 32 + f], v1);
      atomicAdd(&acc[(p2 & BMASK) * 32 + f], v2);
      atomicAdd(&acc[(p3 & BMASK) * 32 + f], v3);
      if (f == 0) {
        atomicAdd(&ldeg[p0 & BMASK], 1u);
        atomicAdd(&ldeg[p1 & BMASK], 1u);
        atomicAdd(&ldeg[p2 & BMASK], 1u);
        atomicAdd(&ldeg[p3 & BMASK], 1u);
      }
    }
    for (unsigned t = j; t < end && t < j + 8; ++t) {
      unsigned p = ep[t];
      if (half == 0) {
        float v = val[(size_t)(p >> BSH) * 32 + f];
        atomicAdd(&acc[(p & BMASK) * 32 + f], v);
        if (f == 0) atomicAdd(&ldeg[p & BMASK], 1u);
      }
    }
  }
  __syncthreads();

  constexpr int ROWS = 256 / F;
  const int f = tid & (F - 1);
  for (int i = tid / F; i < 128; i += ROWS) {
    int gnode = blockIdx.x * 128 + i;
    if (gnode >= N) break;
    unsigned d = ldeg[i];
    float inv = d ? 1.f / (float)d : 0.f;
    float v = acc[i * F + f] * inv;
    if (ADD_BASE) v += basep[(size_t)gnode * F + f];
    out[(size_t)gnode * F + f] = v;
  }
}

extern "C" void kernel_launch(void* const* d_in, const int* in_sizes, int n_in,
                              void* d_out, int out_size, void* d_ws,
                              size_t ws_size, hipStream_t stream) {
  const float* x   = (const float*)d_in[0];
  const int*   ei  = (const int*)d_in[1];  // [2, E]: row0 = src, row1 = dst
  const float* W1n = (const float*)d_in[2];
  const float* W1s = (const float*)d_in[3];
  const float* b1  = (const float*)d_in[4];
  const float* W2n = (const float*)d_in[5];
  const float* W2s = (const float*)d_in[6];
  const float* b2  = (const float*)d_in[7];
  float* out = (float*)d_out;

  const int E = in_sizes[1] / 2;  // 1,600,000
  const int M = N_NODES;
  const int* src = ei;
  const int* dst = ei + E;

  // Workspace layout (bytes):
  //   ep    @ 0           6,400,000  (packed bucket-sorted edges)
  //   mean1 @ 6,400,000  25,600,000  (layer2: hn @6.4M [12.8M], hs @19.2M [12.8M])
  //   h     @ 32,000,000 25,600,000
  //   bcnt  @ 57,600,000      3,136
  //   boff  @ 57,604,096      3,140
  //   bcur  @ 57,608,192      3,136
  char* wsb = (char*)d_ws;
  unsigned* ep    = (unsigned*)(wsb);
  float*    mean1 = (float*)(wsb + 6400000);
  float*    h     = (float*)(wsb + 32000000);
  unsigned* bcnt  = (unsigned*)(wsb + 57600000);
  unsigned* boff  = (unsigned*)(wsb + 57604096);
  unsigned* bcur  = (unsigned*)(wsb + 57608192);
  float* hn = (float*)(wsb + 6400000);   // [M x 32]
  float* hs = (float*)(wsb + 19200000);  // [M x 32]

  const int EB = (E + 16383) / 16384;  // 98

  // ---- bucket-ordered edge list (shared by both layers) ----
  hipMemsetAsync(bcnt, 0, NB * 4, stream);
  bhist_k<<<EB, 1024, 0, stream>>>(dst, bcnt, E);
  bscan_k<<<1, 1024, 0, stream>>>(bcnt, boff, bcur);
  bscatter_k<<<EB, 1024, 0, stream>>>(src, dst, bcur, ep, E);

  // ---- Layer 1: mean1 = mean(x[src]) ; h = relu(mean1@W1n + x@W1s + b1) ----
  agg_k<6, false><<<NB, 256, 0, stream>>>(x, ep, boff, nullptr, mean1, M);
  gemm1_k<<<(M + 15) / 16, 256, 0, stream>>>(mean1, x, W1n, W1s, b1, h, M);

  // ---- Layer 2: hn/hs = h@{W2n,W2s}+b2 ; out = mean(hn[src]) + hs ----
  gemm2_k<<<(M + 31) / 32, 256, 0, stream>>>(h, W2n, W2s, b2, hn, hs, M);
  agg_k<5, true><<<NB, 256, 0, stream>>>(hn, ep, boff, hs, out, M);
}

// Round 5
// 344.339 us; speedup vs baseline: 3.7345x; 3.7345x over previous
//
#include <hip/hip_runtime.h>
#include <hip/hip_bf16.h>

#define N_NODES 100000
#define NB 784   // buckets of 128 nodes: 784*128 = 100352 >= N_NODES
#define NPAD 100352
#define BSH 7
#define BMASK 127

// ---------------------------------------------------------------------------
// Fused dual-GEMM, layer 1:
//   h[r][c] = relu( mean1[r]@W1n[:,c] + x[r]@W1s[:,c] + b1[c] )
// ---------------------------------------------------------------------------
__global__ __launch_bounds__(256) void gemm1_k(
    const float* __restrict__ mean1, const float* __restrict__ x,
    const float* __restrict__ W1n, const float* __restrict__ W1s,
    const float* __restrict__ b1, float* __restrict__ h, int M) {
  __shared__ float Wn[64 * 64];
  __shared__ float Ws[64 * 64];
  const int tid = threadIdx.x;
  for (int i = tid; i < 64 * 64; i += 256) {
    Wn[i] = W1n[i];
    Ws[i] = W1s[i];
  }
  __syncthreads();

  const int col = tid & 63;
  const int g = tid >> 6;
  const long long row0 = (long long)blockIdx.x * 16 + g * 4;
  if (row0 >= M) return;

  float acc[4] = {0.f, 0.f, 0.f, 0.f};
#pragma unroll
  for (int k4 = 0; k4 < 16; ++k4) {
#pragma unroll
    for (int r = 0; r < 4; ++r) {
      float4 mv = ((const float4*)(mean1 + (row0 + r) * 64))[k4];
      float4 xv = ((const float4*)(x + (row0 + r) * 64))[k4];
      acc[r] = fmaf(mv.x, Wn[(4 * k4 + 0) * 64 + col], acc[r]);
      acc[r] = fmaf(mv.y, Wn[(4 * k4 + 1) * 64 + col], acc[r]);
      acc[r] = fmaf(mv.z, Wn[(4 * k4 + 2) * 64 + col], acc[r]);
      acc[r] = fmaf(mv.w, Wn[(4 * k4 + 3) * 64 + col], acc[r]);
      acc[r] = fmaf(xv.x, Ws[(4 * k4 + 0) * 64 + col], acc[r]);
      acc[r] = fmaf(xv.y, Ws[(4 * k4 + 1) * 64 + col], acc[r]);
      acc[r] = fmaf(xv.z, Ws[(4 * k4 + 2) * 64 + col], acc[r]);
      acc[r] = fmaf(xv.w, Ws[(4 * k4 + 3) * 64 + col], acc[r]);
    }
  }
  const float b = b1[col];
#pragma unroll
  for (int r = 0; r < 4; ++r)
    h[(row0 + r) * 64 + col] = fmaxf(acc[r] + b, 0.f);
}

// ---------------------------------------------------------------------------
// Fused dual-GEMM, layer 2: hn = h@W2n ; hs = h@W2s + b2
// ---------------------------------------------------------------------------
__global__ __launch_bounds__(256) void gemm2_k(
    const float* __restrict__ h, const float* __restrict__ W2n,
    const float* __restrict__ W2s, const float* __restrict__ b2,
    float* __restrict__ hn, float* __restrict__ hs, int M) {
  __shared__ float Wn[64 * 32];
  __shared__ float Ws[64 * 32];
  const int tid = threadIdx.x;
  for (int i = tid; i < 64 * 32; i += 256) {
    Wn[i] = W2n[i];
    Ws[i] = W2s[i];
  }
  __syncthreads();

  const int col = tid & 31;
  const int g = tid >> 5;
  const long long row0 = (long long)blockIdx.x * 32 + g * 4;
  if (row0 >= M) return;

  float an[4] = {0.f, 0.f, 0.f, 0.f};
  float as[4] = {0.f, 0.f, 0.f, 0.f};
#pragma unroll
  for (int k4 = 0; k4 < 16; ++k4) {
#pragma unroll
    for (int r = 0; r < 4; ++r) {
      float4 v = ((const float4*)(h + (row0 + r) * 64))[k4];
      an[r] = fmaf(v.x, Wn[(4 * k4 + 0) * 32 + col], an[r]);
      an[r] = fmaf(v.y, Wn[(4 * k4 + 1) * 32 + col], an[r]);
      an[r] = fmaf(v.z, Wn[(4 * k4 + 2) * 32 + col], an[r]);
      an[r] = fmaf(v.w, Wn[(4 * k4 + 3) * 32 + col], an[r]);
      as[r] = fmaf(v.x, Ws[(4 * k4 + 0) * 32 + col], as[r]);
      as[r] = fmaf(v.y, Ws[(4 * k4 + 1) * 32 + col], as[r]);
      as[r] = fmaf(v.z, Ws[(4 * k4 + 2) * 32 + col], as[r]);
      as[r] = fmaf(v.w, Ws[(4 * k4 + 3) * 32 + col], as[r]);
    }
  }
  const float b = b2[col];
#pragma unroll
  for (int r = 0; r < 4; ++r) {
    hn[(row0 + r) * 32 + col] = an[r];
    hs[(row0 + r) * 32 + col] = as[r] + b;
  }
}

// ------------------------- phase 1: coarse buckets -------------------------
__global__ __launch_bounds__(1024) void bhist_k(const int* __restrict__ dst,
                                                unsigned* __restrict__ bcnt,
                                                int E) {
  __shared__ unsigned lh[NB];
  for (int i = threadIdx.x; i < NB; i += 1024) lh[i] = 0;
  __syncthreads();
  const int base = blockIdx.x * 16384;
#pragma unroll
  for (int it = 0; it < 16; ++it) {
    int e = base + it * 1024 + threadIdx.x;
    if (e < E) atomicAdd(&lh[((unsigned)dst[e]) >> BSH], 1u);
  }
  __syncthreads();
  for (int i = threadIdx.x; i < NB; i += 1024)
    if (lh[i]) atomicAdd(&bcnt[i], lh[i]);
}

__global__ __launch_bounds__(1024) void bscan_k(const unsigned* __restrict__ bcnt,
                                                unsigned* __restrict__ boff,
                                                unsigned* __restrict__ bcur) {
  __shared__ unsigned s[1024];
  const int tid = threadIdx.x;
  unsigned v = (tid < NB) ? bcnt[tid] : 0u;
  s[tid] = v;
  __syncthreads();
  for (int off = 1; off < 1024; off <<= 1) {
    unsigned t = (tid >= off) ? s[tid - off] : 0u;
    __syncthreads();
    s[tid] += t;
    __syncthreads();
  }
  unsigned ex = s[tid] - v;
  if (tid < NB) {
    boff[tid] = ex;
    bcur[tid] = ex;
  }
  if (tid == NB - 1) boff[NB] = ex + v;
}

// Scatter packed edges (src<<7 | dst&127) into bucket-ordered ep[].
// Each block reserves a contiguous run per bucket -> block-private write runs.
__global__ __launch_bounds__(1024) void bscatter_k(const int* __restrict__ src,
                                                   const int* __restrict__ dst,
                                                   unsigned* __restrict__ bcur,
                                                   unsigned* __restrict__ ep,
                                                   int E) {
  __shared__ unsigned lh[NB];
  __shared__ unsigned lbase[NB];
  for (int i = threadIdx.x; i < NB; i += 1024) lh[i] = 0;
  __syncthreads();
  const int base = blockIdx.x * 16384;
  unsigned short rank[16];
  unsigned short bb[16];
#pragma unroll
  for (int it = 0; it < 16; ++it) {
    int e = base + it * 1024 + threadIdx.x;
    if (e < E) {
      unsigned b = ((unsigned)dst[e]) >> BSH;
      bb[it] = (unsigned short)b;
      rank[it] = (unsigned short)atomicAdd(&lh[b], 1u);
    }
  }
  __syncthreads();
  for (int i = threadIdx.x; i < NB; i += 1024)
    lbase[i] = lh[i] ? atomicAdd(&bcur[i], lh[i]) : 0u;
  __syncthreads();
#pragma unroll
  for (int it = 0; it < 16; ++it) {
    int e = base + it * 1024 + threadIdx.x;
    if (e < E) {
      unsigned b = bb[it];
      ep[lbase[b] + rank[it]] =
          (((unsigned)src[e]) << BSH) | (((unsigned)dst[e]) & BMASK);
    }
  }
}

// ------------------------- phase 2: in-bucket sort -------------------------
// One block per bucket: counting-sort ~2040 packed edges by dst&127 in LDS,
// emit dst-sorted src ids (ssrc) + row offsets. All global stores land in a
// block-private window -> no cross-XCD line bouncing.
__global__ __launch_bounds__(256) void bsort_k(const unsigned* __restrict__ ep,
                                               const unsigned* __restrict__ boff,
                                               int* __restrict__ ssrc,
                                               unsigned* __restrict__ rows) {
  __shared__ unsigned cnt[128];
  __shared__ unsigned sc[128];
  const int tid = threadIdx.x;
  const unsigned beg = boff[blockIdx.x], end = boff[blockIdx.x + 1];
  if (tid < 128) cnt[tid] = 0;
  __syncthreads();
  for (unsigned j = beg + tid; j < end; j += 256)
    atomicAdd(&cnt[ep[j] & BMASK], 1u);
  __syncthreads();
  // exclusive scan of 128 counters (Hillis-Steele, barriers over all threads)
  unsigned v = (tid < 128) ? cnt[tid] : 0u;
  if (tid < 128) sc[tid] = v;
  __syncthreads();
  for (int off = 1; off < 128; off <<= 1) {
    unsigned t = (tid < 128 && tid >= off) ? sc[tid - off] : 0u;
    __syncthreads();
    if (tid < 128) sc[tid] += t;
    __syncthreads();
  }
  unsigned ex = sc[tid] - v;  // exclusive (tid<128)
  if (tid < 128) {
    rows[blockIdx.x * 128 + tid] = beg + ex;
    cnt[tid] = ex;  // becomes the scatter cursor
  }
  __syncthreads();
  for (unsigned j = beg + tid; j < end; j += 256) {
    unsigned p = ep[j];
    unsigned r = atomicAdd(&cnt[p & BMASK], 1u);
    ssrc[beg + r] = (int)(p >> BSH);
  }
}

// ---------------------------------------------------------------------------
// Gather-mean, 8 clamped loads always in flight (deg~16, latency-bound):
//   out[node][f] = (1/deg)*sum_j val[ssrc[j]][f]  (+ base[node][f])
// ---------------------------------------------------------------------------
template <int LOGF, bool ADD_BASE>
__global__ __launch_bounds__(256) void gather_k(
    const float* __restrict__ val, const int* __restrict__ ssrc,
    const unsigned* __restrict__ rows, const float* __restrict__ base,
    float* __restrict__ out, int N) {
  constexpr int F = 1 << LOGF;
  const int node = blockIdx.x * (256 >> LOGF) + (threadIdx.x >> LOGF);
  const int f = threadIdx.x & (F - 1);
  if (node >= N) return;
  const unsigned beg = rows[node], end = rows[node + 1];
  float acc = 0.f;
  if (end > beg) {
    const unsigned last = end - 1;
    for (unsigned j = beg; j < end; j += 8) {
      float s = 0.f;
#pragma unroll
      for (int i = 0; i < 8; ++i) {
        unsigned jj = j + i;
        unsigned idx = jj < last ? jj : last;  // clamp: load always issued
        int sn = ssrc[idx];
        float vv = val[((size_t)sn << LOGF) | f];
        s += (jj < end) ? vv : 0.f;            // predicate the add only
      }
      acc += s;
    }
  }
  const unsigned dg = end - beg;
  const float inv = dg ? 1.f / (float)dg : 0.f;
  float v = acc * inv;
  if (ADD_BASE) v += base[((size_t)node << LOGF) | f];
  out[((size_t)node << LOGF) | f] = v;
}

extern "C" void kernel_launch(void* const* d_in, const int* in_sizes, int n_in,
                              void* d_out, int out_size, void* d_ws,
                              size_t ws_size, hipStream_t stream) {
  const float* x   = (const float*)d_in[0];
  const int*   ei  = (const int*)d_in[1];  // [2, E]: row0 = src, row1 = dst
  const float* W1n = (const float*)d_in[2];
  const float* W1s = (const float*)d_in[3];
  const float* b1  = (const float*)d_in[4];
  const float* W2n = (const float*)d_in[5];
  const float* W2s = (const float*)d_in[6];
  const float* b2  = (const float*)d_in[7];
  float* out = (float*)d_out;

  const int E = in_sizes[1] / 2;  // 1,600,000
  const int M = N_NODES;
  const int* src = ei;
  const int* dst = ei + E;

  // Workspace layout (bytes):
  //   ep    @ 0           6,400,000
  //   ssrc  @ 6,400,000   6,400,000
  //   rows  @ 12,800,000    401,412  ((NPAD+1) u32)
  //   bcnt  @ 13,203,456      3,136
  //   boff  @ 13,207,552      3,140
  //   bcur  @ 13,211,648      3,136
  //   mean1 @ 13,215,744 25,600,000  (layer2: hn @13,215,744 [12.8M], hs @26,015,744 [12.8M])
  //   h     @ 38,815,744 25,600,000
  char* wsb = (char*)d_ws;
  unsigned* ep    = (unsigned*)(wsb);
  int*      ssrc  = (int*)(wsb + 6400000);
  unsigned* rows  = (unsigned*)(wsb + 12800000);
  unsigned* bcnt  = (unsigned*)(wsb + 13203456);
  unsigned* boff  = (unsigned*)(wsb + 13207552);
  unsigned* bcur  = (unsigned*)(wsb + 13211648);
  float*    mean1 = (float*)(wsb + 13215744);
  float*    h     = (float*)(wsb + 38815744);
  float* hn = (float*)(wsb + 13215744);  // [M x 32]
  float* hs = (float*)(wsb + 26015744);  // [M x 32]

  const int EB = (E + 16383) / 16384;  // 98

  // ---- dst-sorted edge list (CSR), block-private writes only ----
  hipMemsetAsync(bcnt, 0, NB * 4, stream);
  bhist_k<<<EB, 1024, 0, stream>>>(dst, bcnt, E);
  bscan_k<<<1, 1024, 0, stream>>>(bcnt, boff, bcur);
  bscatter_k<<<EB, 1024, 0, stream>>>(src, dst, bcur, ep, E);
  bsort_k<<<NB, 256, 0, stream>>>(ep, boff, ssrc, rows);

  // ---- Layer 1: mean1 = mean(x[src]) ; h = relu(mean1@W1n + x@W1s + b1) ----
  gather_k<6, false><<<M / 4, 256, 0, stream>>>(x, ssrc, rows, nullptr, mean1, M);
  gemm1_k<<<(M + 15) / 16, 256, 0, stream>>>(mean1, x, W1n, W1s, b1, h, M);

  // ---- Layer 2: hn/hs = h@{W2n,W2s}+b2 ; out = mean(hn[src]) + hs ----
  gemm2_k<<<(M + 31) / 32, 256, 0, stream>>>(h, W2n, W2s, b2, hn, hs, M);
  gather_k<5, true><<<M / 8, 256, 0, stream>>>(hn, ssrc, rows, hs, out, M);
}